// Round 4
// baseline (373.671 us; speedup 1.0000x reference)
//
#include <hip/hip_runtime.h>

// GCN encoder: h1 = relu(x@fcW+fcb); h2 = relu(gcn(h1,W1,b1)); out = relu(gcn(h2,W2,b2))
// gcn(x,W,b)[i] = sum_{e:dst=i} (x@W)[src_e]*norm_e + (x@W)[i]*dinv[i]^2 + b
// Aggregation: dst-sorted CSR built on device, per-node gather (no fp32 atomics).
// GEMM: 128x128 (or 128x64) tile, BK=8, 256 thr, 8x8/thread, reg-staged dbuf.

namespace {
constexpr int NN = 20000;
constexpr int NE = 320000;
constexpr int IN_FT = 256, HID1 = 400, HID2 = 200, OUT_FT = 128;
}

// deg (weighted, +1 self loop) and integer count per dst in one pass
__global__ __launch_bounds__(256) void deg_count_kernel(const int* __restrict__ dst,
                                                        const float* __restrict__ ew,
                                                        float* __restrict__ deg,
                                                        int* __restrict__ cnt) {
  int tid = blockIdx.x * 256 + threadIdx.x;
  if (tid < NE) {
    int d = dst[tid];
    unsafeAtomicAdd(&deg[d], ew[tid]);
    atomicAdd(&cnt[d], 1);
  } else if (tid < NE + NN) {
    unsafeAtomicAdd(&deg[tid - NE], 1.0f);  // self-loop weight 1
  }
}

__global__ __launch_bounds__(256) void dinv_kernel(float* __restrict__ deg) {
  int i = blockIdx.x * 256 + threadIdx.x;
  if (i < NN) {
    float d = deg[i];
    deg[i] = d > 0.f ? rsqrtf(d) : 0.f;  // in place: deg -> dinv
  }
}

__global__ __launch_bounds__(256) void norm_kernel(const int* __restrict__ src,
                                                   const int* __restrict__ dst,
                                                   const float* __restrict__ ew,
                                                   const float* __restrict__ dinv,
                                                   float* __restrict__ nrm) {
  int e = blockIdx.x * 256 + threadIdx.x;
  if (e < NE) {
    nrm[e] = dinv[src[e]] * ew[e] * dinv[dst[e]];
  }
}

// single-block exclusive scan of count[NN] -> rowptr[NN+1]
__global__ __launch_bounds__(1024) void scan_kernel(const int* __restrict__ count,
                                                    int* __restrict__ rowptr) {
  constexpr int CHUNK = (NN + 1023) / 1024;  // 20
  __shared__ int partial[1024];
  const int t = threadIdx.x;
  const int base = t * CHUNK;
  int s = 0;
#pragma unroll
  for (int i = 0; i < CHUNK; ++i) {
    int idx = base + i;
    if (idx < NN) s += count[idx];
  }
  partial[t] = s;
  __syncthreads();
  for (int off = 1; off < 1024; off <<= 1) {
    int v = 0;
    if (t >= off) v = partial[t - off];
    __syncthreads();
    if (t >= off) partial[t] += v;
    __syncthreads();
  }
  int excl = partial[t] - s;
#pragma unroll
  for (int i = 0; i < CHUNK; ++i) {
    int idx = base + i;
    if (idx < NN) {
      rowptr[idx] = excl;
      excl += count[idx];
    }
  }
  if (t == 1023) rowptr[NN] = partial[1023];
}

__global__ __launch_bounds__(256) void scatter_kernel(const int* __restrict__ src,
                                                      const int* __restrict__ dst,
                                                      const float* __restrict__ nrm,
                                                      int* __restrict__ fill,
                                                      int* __restrict__ srcS,
                                                      float* __restrict__ wS) {
  int e = blockIdx.x * 256 + threadIdx.x;
  if (e >= NE) return;
  int d = dst[e];
  int pos = atomicAdd(&fill[d], 1);
  srcS[pos] = src[e];
  wS[pos] = nrm[e];
}

// C[M,Nc] = A[M,K] @ B[K,Nc] (+bias)(relu).
// 128 x BN tile, BK=8, 256 threads, per-thread 8 x (BN/16), reg-staged LDS dbuf.
// Requires K % 8 == 0, Nc % 4 == 0.
template <int BN, bool BIAS, bool RELU>
__global__ __launch_bounds__(256) void gemm_tile_kernel(const float* __restrict__ A,
                                                        const float* __restrict__ B,
                                                        const float* __restrict__ bias,
                                                        float* __restrict__ C,
                                                        int M, int K, int Nc) {
  constexpr int NQ = BN / 64;  // col quadrants (1 or 2)
  __shared__ float As[8][128];  // [k][m]
  __shared__ float Bs[8][BN];   // [k][n]
  const int tid = threadIdx.x;
  const int tx = tid & 15, ty = tid >> 4;
  const int m0 = blockIdx.y * 128, n0 = blockIdx.x * BN;

  // A staging indices: each thread one float4
  const int ar = tid >> 1;            // 0..127 row in tile
  const int akq = (tid & 1) * 4;      // k offset 0 or 4
  const int am = m0 + ar;
  // B staging indices
  const int bkk = (BN == 128) ? (tid >> 5) : (tid >> 4);  // k row
  const int bc = (BN == 128) ? ((tid & 31) * 4) : ((tid & 15) * 4);
  const bool bact = (BN == 128) ? true : (tid < 128);
  const int bn = n0 + bc;

  const int KT = K >> 3;

  float acc[2][NQ][4][4];
#pragma unroll
  for (int qi = 0; qi < 2; ++qi)
#pragma unroll
    for (int qj = 0; qj < NQ; ++qj)
#pragma unroll
      for (int i = 0; i < 4; ++i)
#pragma unroll
        for (int j = 0; j < 4; ++j) acc[qi][qj][i][j] = 0.f;

  float4 aR = make_float4(0.f, 0.f, 0.f, 0.f);
  float4 bR = make_float4(0.f, 0.f, 0.f, 0.f);
  // prologue: tile 0
  if (am < M) aR = *reinterpret_cast<const float4*>(A + (size_t)am * K + akq);
  if (bact && bn < Nc) bR = *reinterpret_cast<const float4*>(B + (size_t)bkk * Nc + bn);
  As[akq + 0][ar] = aR.x;
  As[akq + 1][ar] = aR.y;
  As[akq + 2][ar] = aR.z;
  As[akq + 3][ar] = aR.w;
  if (bact) *reinterpret_cast<float4*>(&Bs[bkk][bc]) = bR;
  __syncthreads();

  for (int kt = 0; kt < KT; ++kt) {
    const bool more = (kt + 1 < KT);
    if (more) {
      const int k = (kt + 1) * 8;
      aR = make_float4(0.f, 0.f, 0.f, 0.f);
      bR = make_float4(0.f, 0.f, 0.f, 0.f);
      if (am < M) aR = *reinterpret_cast<const float4*>(A + (size_t)am * K + k + akq);
      if (bact && bn < Nc) bR = *reinterpret_cast<const float4*>(B + (size_t)(k + bkk) * Nc + bn);
    }
#pragma unroll
    for (int kk = 0; kk < 8; ++kk) {
      float4 a0 = *reinterpret_cast<const float4*>(&As[kk][ty * 4]);
      float4 a1 = *reinterpret_cast<const float4*>(&As[kk][64 + ty * 4]);
      float4 b0 = *reinterpret_cast<const float4*>(&Bs[kk][tx * 4]);
      float4 b1;
      if (NQ == 2) b1 = *reinterpret_cast<const float4*>(&Bs[kk][64 + tx * 4]);
      const float av[2][4] = {{a0.x, a0.y, a0.z, a0.w}, {a1.x, a1.y, a1.z, a1.w}};
      float bv[NQ][4];
      bv[0][0] = b0.x; bv[0][1] = b0.y; bv[0][2] = b0.z; bv[0][3] = b0.w;
      if (NQ == 2) { bv[1][0] = b1.x; bv[1][1] = b1.y; bv[1][2] = b1.z; bv[1][3] = b1.w; }
#pragma unroll
      for (int qi = 0; qi < 2; ++qi)
#pragma unroll
        for (int i = 0; i < 4; ++i)
#pragma unroll
          for (int qj = 0; qj < NQ; ++qj)
#pragma unroll
            for (int j = 0; j < 4; ++j)
              acc[qi][qj][i][j] = fmaf(av[qi][i], bv[qj][j], acc[qi][qj][i][j]);
    }
    __syncthreads();
    if (more) {
      As[akq + 0][ar] = aR.x;
      As[akq + 1][ar] = aR.y;
      As[akq + 2][ar] = aR.z;
      As[akq + 3][ar] = aR.w;
      if (bact) *reinterpret_cast<float4*>(&Bs[bkk][bc]) = bR;
      __syncthreads();
    }
  }

  // epilogue
#pragma unroll
  for (int qj = 0; qj < NQ; ++qj) {
    const int n = n0 + qj * 64 + tx * 4;
    if (n >= Nc) continue;
    float4 bb = make_float4(0.f, 0.f, 0.f, 0.f);
    if (BIAS) bb = *reinterpret_cast<const float4*>(bias + n);
#pragma unroll
    for (int qi = 0; qi < 2; ++qi)
#pragma unroll
      for (int i = 0; i < 4; ++i) {
        const int m = m0 + qi * 64 + ty * 4 + i;
        if (m >= M) continue;
        float4 v = make_float4(acc[qi][qj][i][0], acc[qi][qj][i][1],
                               acc[qi][qj][i][2], acc[qi][qj][i][3]);
        if (BIAS) { v.x += bb.x; v.y += bb.y; v.z += bb.z; v.w += bb.w; }
        if (RELU) {
          v.x = fmaxf(v.x, 0.f); v.y = fmaxf(v.y, 0.f);
          v.z = fmaxf(v.z, 0.f); v.w = fmaxf(v.w, 0.f);
        }
        *reinterpret_cast<float4*>(C + (size_t)m * Nc + n) = v;
      }
  }
}

// Fused gather-aggregate + self-loop + bias + relu. One 64-lane wave per node.
template <int F>
__global__ __launch_bounds__(256) void agg_gather_kernel(const int* __restrict__ rowptr,
                                                         const int* __restrict__ srcS,
                                                         const float* __restrict__ wS,
                                                         const float* __restrict__ t,
                                                         const float* __restrict__ dinv,
                                                         const float* __restrict__ bias,
                                                         float* __restrict__ out) {
  constexpr int NITER = (F + 63) / 64;
  const int wv = threadIdx.x >> 6, lane = threadIdx.x & 63;
  const int node = blockIdx.x * 4 + wv;
  if (node >= NN) return;
  const int beg = rowptr[node], end = rowptr[node + 1];
  float acc[NITER];
#pragma unroll
  for (int i = 0; i < NITER; ++i) acc[i] = 0.f;
  for (int j = beg; j < end; ++j) {
    const int s = srcS[j];
    const float wgt = wS[j];
    const float* row = t + (size_t)s * F;
#pragma unroll
    for (int i = 0; i < NITER; ++i) {
      int f = lane + i * 64;
      if (f < F) acc[i] += row[f] * wgt;
    }
  }
  const float di = dinv[node];
  const float self_w = di * di;
  const float* trow = t + (size_t)node * F;
  float* orow = out + (size_t)node * F;
#pragma unroll
  for (int i = 0; i < NITER; ++i) {
    int f = lane + i * 64;
    if (f < F) {
      float v = fmaf(trow[f], self_w, acc[i]) + bias[f];
      orow[f] = fmaxf(v, 0.f);
    }
  }
}

extern "C" void kernel_launch(void* const* d_in, const int* in_sizes, int n_in,
                              void* d_out, int out_size, void* d_ws, size_t ws_size,
                              hipStream_t stream) {
  const float* x = (const float*)d_in[0];
  const int* ei = (const int*)d_in[1];  // int32 per harness conversion
  const float* ea = (const float*)d_in[2];
  const float* fcW = (const float*)d_in[3];
  const float* fcb = (const float*)d_in[4];
  const float* W1 = (const float*)d_in[5];
  const float* b1 = (const float*)d_in[6];
  const float* W2 = (const float*)d_in[7];
  const float* b2 = (const float*)d_in[8];
  const int* srcIdx = ei;       // edge_index[0]
  const int* dstIdx = ei + NE;  // edge_index[1]

  char* ws = (char*)d_ws;
  constexpr size_t MB = 1u << 20;
  float* dinv = (float*)(ws);            // 80 KB
  float* nrm = (float*)(ws + 1 * MB);    // 1.28 MB
  int* rowptr = (int*)(ws + 3 * MB);     // 80 KB (NN+1)
  int* cnt = (int*)(ws + 4 * MB);        // 80 KB (count, then fill cursor)
  int* srcS = (int*)(ws + 5 * MB);       // 1.28 MB
  float* wS = (float*)(ws + 7 * MB);     // 1.28 MB
  float* bufA = (float*)(ws + 9 * MB);   // 32 MB: h1 [N,400] -> h2 [N,200]
  float* bufB = (float*)(ws + 41 * MB);  // 16 MB: t1 [N,200] -> t2 [N,128]
  // peak ws use: 57 MB

  // --- normalization + CSR (shared by both GCN layers) ---
  hipMemsetAsync(dinv, 0, NN * sizeof(float), stream);
  hipMemsetAsync(cnt, 0, NN * sizeof(int), stream);
  deg_count_kernel<<<(NE + NN + 255) / 256, 256, 0, stream>>>(dstIdx, ea, dinv, cnt);
  dinv_kernel<<<(NN + 255) / 256, 256, 0, stream>>>(dinv);
  norm_kernel<<<(NE + 255) / 256, 256, 0, stream>>>(srcIdx, dstIdx, ea, dinv, nrm);
  scan_kernel<<<1, 1024, 0, stream>>>(cnt, rowptr);
  hipMemcpyAsync(cnt, rowptr, NN * sizeof(int), hipMemcpyDeviceToDevice, stream);
  scatter_kernel<<<(NE + 255) / 256, 256, 0, stream>>>(srcIdx, dstIdx, nrm, cnt, srcS, wS);

  const int MB128 = (NN + 127) / 128;  // 157 row blocks

  // --- h1 = relu(x @ fcW + fcb) ---
  float* h1 = bufA;
  gemm_tile_kernel<128, true, true><<<dim3((HID1 + 127) / 128, MB128), 256, 0, stream>>>(
      x, fcW, fcb, h1, NN, IN_FT, HID1);

  // --- layer 1: t1 = h1 @ W1; h2 = relu(agg(t1) + t1*dinv^2 + b1) ---
  float* t1 = bufB;
  gemm_tile_kernel<128, false, false><<<dim3((HID2 + 127) / 128, MB128), 256, 0, stream>>>(
      h1, W1, nullptr, t1, NN, HID1, HID2);
  float* h2 = bufA;  // h1 dead after t1 GEMM
  agg_gather_kernel<HID2><<<(NN + 3) / 4, 256, 0, stream>>>(
      rowptr, srcS, wS, t1, dinv, b1, h2);

  // --- layer 2: t2 = h2 @ W2; out = relu(agg(t2) + t2*dinv^2 + b2) ---
  float* t2 = bufB;  // t1 dead after agg1
  gemm_tile_kernel<64, false, false><<<dim3((OUT_FT + 63) / 64, MB128), 256, 0, stream>>>(
      h2, W2, nullptr, t2, NN, HID2, OUT_FT);
  agg_gather_kernel<OUT_FT><<<(NN + 3) / 4, 256, 0, stream>>>(
      rowptr, srcS, wS, t2, dinv, b2, (float*)d_out);
}